// Round 1
// 199.861 us; speedup vs baseline: 1.0270x; 1.0270x over previous
//
#include <hip/hip_runtime.h>

typedef unsigned short ushort_t;
typedef unsigned int uint_t;

#define BKT_SHIFT 8            // 256 dst-nodes per bucket
#define BKT_NODES 256
#define NBKT_MAX 400           // >= ceil(100000/256)=391
#define EPB 8192               // edges per block in hist/scatter (512 thr x 16)
#define SCOL_CAP 8192          // LDS col staging in fine_fill (32 KB); mean bucket = 6400
#define NPB16 64               // nodes per block in agg_mlp16
#define SCOL_N16 2560          // LDS col cache per agg block (mean 1600, +24 sigma)

__device__ __forceinline__ ushort_t f2bf(float f) {
    unsigned u = __float_as_uint(f);
    unsigned r = (u + 0x7FFFu + ((u >> 16) & 1u)) >> 16;   // RNE
    return (ushort_t)r;
}
__device__ __forceinline__ float bflo(uint_t u) { return __uint_as_float(u << 16); }
__device__ __forceinline__ float bfhi(uint_t u) { return __uint_as_float(u & 0xFFFF0000u); }

// ---- z1 = x @ W1  (32 -> 16), bf16 out ---------------------------------
// GIN trick: (x_i + sum x_j)@W1 + b1 = z1_i + sum z1_j + b1, so aggregate in
// 16-ch z-space (32 B/row -> halved gather traffic, table L2-resident).
__global__ void lin_in(const float4* __restrict__ x4, const float* __restrict__ W,
                       ushort_t* __restrict__ z, int N) {
    __shared__ float sW[32 * 16];
    int t = threadIdx.x;
    sW[t] = W[t];
    sW[t + 256] = W[t + 256];
    __syncthreads();
    int n = blockIdx.x * 256 + t;
    if (n >= N) return;
    float acc[16];
    #pragma unroll
    for (int c = 0; c < 16; ++c) acc[c] = 0.f;
    const float4* xr = x4 + (size_t)n * 8;
    #pragma unroll
    for (int k4 = 0; k4 < 8; ++k4) {
        float4 xv = xr[k4];
        #pragma unroll
        for (int c = 0; c < 16; ++c) {
            acc[c] += xv.x * sW[(k4 * 4 + 0) * 16 + c];
            acc[c] += xv.y * sW[(k4 * 4 + 1) * 16 + c];
            acc[c] += xv.z * sW[(k4 * 4 + 2) * 16 + c];
            acc[c] += xv.w * sW[(k4 * 4 + 3) * 16 + c];
        }
    }
    uint_t w[8];
    #pragma unroll
    for (int i = 0; i < 8; ++i)
        w[i] = (uint_t)f2bf(acc[2 * i]) | ((uint_t)f2bf(acc[2 * i + 1]) << 16);
    uint4* zo = (uint4*)(z + (size_t)n * 16);
    uint4 a; a.x = w[0]; a.y = w[1]; a.z = w[2]; a.w = w[3];
    uint4 b; b.x = w[4]; b.y = w[5]; b.z = w[6]; b.w = w[7];
    zo[0] = a;          // keep cacheable: consumed by agg gather next
    zo[1] = b;
}

// ---- ranked bucket sort (no global atomics) -----------------------------

__global__ void histA(const int* __restrict__ dst, int* __restrict__ hist,
                      int E, int NBKT) {
    __shared__ int lcnt[NBKT_MAX];
    int t = threadIdx.x, blk = blockIdx.x;
    for (int b = t; b < NBKT; b += 512) lcnt[b] = 0;
    __syncthreads();
    int e0 = blk * EPB;
    #pragma unroll
    for (int i = 0; i < 16; ++i) {
        int e = e0 + i * 512 + t;
        if (e < E) atomicAdd(&lcnt[dst[e] >> BKT_SHIFT], 1);
    }
    __syncthreads();
    for (int b = t; b < NBKT; b += 512) hist[blk * NBKT + b] = lcnt[b];
}

__global__ void colscan(int* __restrict__ hist, int* __restrict__ T,
                        int NBLK, int NBKT) {
    __shared__ int lds[256];
    int b = blockIdx.x, t = threadIdx.x;
    int j0 = t * 4;
    int v0 = (j0 + 0 < NBLK) ? hist[(j0 + 0) * NBKT + b] : 0;
    int v1 = (j0 + 1 < NBLK) ? hist[(j0 + 1) * NBKT + b] : 0;
    int v2 = (j0 + 2 < NBLK) ? hist[(j0 + 2) * NBKT + b] : 0;
    int v3 = (j0 + 3 < NBLK) ? hist[(j0 + 3) * NBKT + b] : 0;
    lds[t] = v0 + v1 + v2 + v3;
    __syncthreads();
    for (int off = 1; off < 256; off <<= 1) {
        int add = (t >= off) ? lds[t - off] : 0;
        __syncthreads();
        lds[t] += add;
        __syncthreads();
    }
    int p = (t == 0) ? 0 : lds[t - 1];
    if (j0 + 0 < NBLK) hist[(j0 + 0) * NBKT + b] = p;  p += v0;
    if (j0 + 1 < NBLK) hist[(j0 + 1) * NBKT + b] = p;  p += v1;
    if (j0 + 2 < NBLK) hist[(j0 + 2) * NBKT + b] = p;  p += v2;
    if (j0 + 3 < NBLK) hist[(j0 + 3) * NBKT + b] = p;
    if (t == 255) T[b] = lds[255];
}

__global__ void scan_small(const int* __restrict__ in, int* __restrict__ out,
                           int M, int E) {
    __shared__ int lds[1024];
    int t = threadIdx.x;
    int base = t * 4;
    int v0 = (base + 0 < M) ? in[base + 0] : 0;
    int v1 = (base + 1 < M) ? in[base + 1] : 0;
    int v2 = (base + 2 < M) ? in[base + 2] : 0;
    int v3 = (base + 3 < M) ? in[base + 3] : 0;
    lds[t] = v0 + v1 + v2 + v3;
    __syncthreads();
    for (int off = 1; off < 1024; off <<= 1) {
        int add = (t >= off) ? lds[t - off] : 0;
        __syncthreads();
        lds[t] += add;
        __syncthreads();
    }
    int p = (t == 0) ? 0 : lds[t - 1];
    if (base + 0 < M) out[base + 0] = p;  p += v0;
    if (base + 1 < M) out[base + 1] = p;  p += v1;
    if (base + 2 < M) out[base + 2] = p;  p += v2;
    if (base + 3 < M) out[base + 3] = p;
    if (t == 0) out[M] = E;
}

__global__ void scatter_kernel(const int* __restrict__ src, const int* __restrict__ dst,
                               const int* __restrict__ hist, const int* __restrict__ Tscan,
                               int* __restrict__ staged, int E, int NBKT) {
    __shared__ int lbase[NBKT_MAX];
    __shared__ int lcur[NBKT_MAX];
    int t = threadIdx.x, blk = blockIdx.x;
    for (int b = t; b < NBKT; b += 512) {
        lbase[b] = hist[blk * NBKT + b] + Tscan[b];
        lcur[b] = 0;
    }
    __syncthreads();
    int e0 = blk * EPB;
    #pragma unroll
    for (int i = 0; i < 16; ++i) {
        int e = e0 + i * 512 + t;
        if (e < E) {
            int d = dst[e], s = src[e];
            int b = d >> BKT_SHIFT;
            int r = atomicAdd(&lcur[b], 1);
            staged[lbase[b] + r] = ((d & (BKT_NODES - 1)) << 24) | s;
        }
    }
}

// One block per bucket: per-(node, src-quartile) LDS count -> 1024-wide scan
// (writes rp!) -> LDS place -> coalesced col flush. The quartile sub-sort
// keeps the gather sweep phase-local in src (L2-friendly; nearly free).
__global__ void fine_fill(const int* __restrict__ staged, const int* __restrict__ Tscan,
                          int* __restrict__ rp, int* __restrict__ col,
                          int N, int E, int NBKT, int q1, int q2, int q3) {
    __shared__ int scnt[1024];   // [node][quartile]
    __shared__ int srel[1024];
    __shared__ int scur[1024];
    __shared__ int swsum[256];
    __shared__ int scol[SCOL_CAP];
    int b = blockIdx.x, t = threadIdx.x;
    int n0 = b << BKT_SHIFT;
    int nn = min(BKT_NODES, N - n0);
    int e0 = Tscan[b];
    int e1 = Tscan[b + 1];
    int m = e1 - e0;

    #pragma unroll
    for (int j = 0; j < 4; ++j) { scnt[t * 4 + j] = 0; scur[t * 4 + j] = 0; }
    __syncthreads();
    for (int i = t; i < m; i += 256) {
        int v = staged[e0 + i];
        int dl = ((unsigned)v) >> 24;
        int s = v & 0xFFFFFF;
        int q = (s >= q2) ? ((s >= q3) ? 3 : 2) : ((s >= q1) ? 1 : 0);
        atomicAdd(&scnt[dl * 4 + q], 1);
    }
    __syncthreads();
    int c0 = scnt[t * 4 + 0], c1 = scnt[t * 4 + 1];
    int c2 = scnt[t * 4 + 2], c3 = scnt[t * 4 + 3];
    int tot = c0 + c1 + c2 + c3;
    swsum[t] = tot;
    __syncthreads();
    for (int off = 1; off < 256; off <<= 1) {   // Hillis-Steele inclusive over nodes
        int add = (t >= off) ? swsum[t - off] : 0;
        __syncthreads();
        swsum[t] += add;
        __syncthreads();
    }
    int excl = swsum[t] - tot;                  // node-exclusive prefix
    srel[t * 4 + 0] = excl;
    srel[t * 4 + 1] = excl + c0;
    srel[t * 4 + 2] = excl + c0 + c1;
    srel[t * 4 + 3] = excl + c0 + c1 + c2;
    if (t < nn) rp[n0 + t] = e0 + excl;
    if (b == NBKT - 1 && t == 0) rp[N] = E;
    __syncthreads();

    if (m <= SCOL_CAP) {
        for (int i = t; i < m; i += 256) {
            int v = staged[e0 + i];
            int dl = ((unsigned)v) >> 24;
            int s = v & 0xFFFFFF;
            int q = (s >= q2) ? ((s >= q3) ? 3 : 2) : ((s >= q1) ? 1 : 0);
            int p = srel[dl * 4 + q] + atomicAdd(&scur[dl * 4 + q], 1);
            scol[p] = s;
        }
        __syncthreads();
        for (int i = t; i < m; i += 256) col[e0 + i] = scol[i];
    } else {  // statistically unreachable overflow fallback
        for (int i = t; i < m; i += 256) {
            int v = staged[e0 + i];
            int dl = ((unsigned)v) >> 24;
            int s = v & 0xFFFFFF;
            int q = (s >= q2) ? ((s >= q3) ? 3 : 2) : ((s >= q1) ? 1 : 0);
            int p = srel[dl * 4 + q] + atomicAdd(&scur[dl * 4 + q], 1);
            col[e0 + p] = s;
        }
    }
}

// ---- Fused 16-ch aggregate + MLP ---------------------------------------
// Block = 256 threads = 64 nodes x 4 lanes; each lane handles 4 channels of
// the 16-ch z-row via uint2 (8B) loads => one gather instr serves 16 edges.
// s = z_i + sum z_j;  h = ReLU(s + ba)         (first Linear pre-distributed)
// o = h @ Wb + bb  (16->32)
//   CHAIN:  z_next = ReLU(o) @ Wc  -> bf16 (feeds next conv's aggregation)
//   !CHAIN: o -> fp32 final output

template <bool CHAIN>
__global__ void agg_mlp16(const ushort_t* __restrict__ zin, const int* __restrict__ rp,
                          const int* __restrict__ col,
                          const float* __restrict__ ba,
                          const float* __restrict__ Wb, const float* __restrict__ bb,
                          const float* __restrict__ Wc,
                          void* __restrict__ outv, int N) {
    __shared__ float sWb[16 * 32];
    __shared__ float sWc[32 * 16];
    __shared__ float sba[16], sbb[32];
    __shared__ float sh[NPB16 * 17];
    __shared__ float sr[NPB16 * 33];
    __shared__ int scol[SCOL_N16];

    int t = threadIdx.x;
    sWb[t] = Wb[t];  sWb[t + 256] = Wb[t + 256];
    if (CHAIN) { sWc[t] = Wc[t];  sWc[t + 256] = Wc[t + 256]; }
    if (t < 16) sba[t] = ba[t];
    if (t < 32) sbb[t] = bb[t];

    int base = blockIdx.x * NPB16;
    int kb = rp[base];
    int kt = rp[min(base + NPB16, N)];
    int tot = kt - kb;
    bool ovf = (tot > SCOL_N16);
    if (!ovf) {
        for (int i = t; i < tot; i += 256)
            scol[i] = __builtin_nontemporal_load(col + kb + i);
    }
    __syncthreads();

    int ln = t >> 2;          // node slot 0..63
    int sl = t & 3;           // channels 4*sl .. 4*sl+3
    int n  = base + ln;
    bool act = (n < N);
    const uint2* zp = (const uint2*)zin;   // row = 4 uint2 (16 bf16)

    if (act) {
        uint2 us = zp[(size_t)n * 4 + sl];
        float v0 = bflo(us.x), v1 = bfhi(us.x), v2 = bflo(us.y), v3 = bfhi(us.y);
        int ks = rp[n], ke = rp[n + 1];
        if (!ovf) {
            int k = ks - kb, kend = ke - kb;
            for (; k + 8 <= kend; k += 8) {
                int s0 = scol[k + 0], s1 = scol[k + 1], s2 = scol[k + 2], s3 = scol[k + 3];
                int s4 = scol[k + 4], s5 = scol[k + 5], s6 = scol[k + 6], s7 = scol[k + 7];
                uint2 u0 = zp[(size_t)s0 * 4 + sl];
                uint2 u1 = zp[(size_t)s1 * 4 + sl];
                uint2 u2 = zp[(size_t)s2 * 4 + sl];
                uint2 u3 = zp[(size_t)s3 * 4 + sl];
                uint2 u4 = zp[(size_t)s4 * 4 + sl];
                uint2 u5 = zp[(size_t)s5 * 4 + sl];
                uint2 u6 = zp[(size_t)s6 * 4 + sl];
                uint2 u7 = zp[(size_t)s7 * 4 + sl];
                v0 += ((bflo(u0.x) + bflo(u1.x)) + (bflo(u2.x) + bflo(u3.x)))
                    + ((bflo(u4.x) + bflo(u5.x)) + (bflo(u6.x) + bflo(u7.x)));
                v1 += ((bfhi(u0.x) + bfhi(u1.x)) + (bfhi(u2.x) + bfhi(u3.x)))
                    + ((bfhi(u4.x) + bfhi(u5.x)) + (bfhi(u6.x) + bfhi(u7.x)));
                v2 += ((bflo(u0.y) + bflo(u1.y)) + (bflo(u2.y) + bflo(u3.y)))
                    + ((bflo(u4.y) + bflo(u5.y)) + (bflo(u6.y) + bflo(u7.y)));
                v3 += ((bfhi(u0.y) + bfhi(u1.y)) + (bfhi(u2.y) + bfhi(u3.y)))
                    + ((bfhi(u4.y) + bfhi(u5.y)) + (bfhi(u6.y) + bfhi(u7.y)));
            }
            for (; k < kend; ++k) {
                uint2 u = zp[(size_t)scol[k] * 4 + sl];
                v0 += bflo(u.x); v1 += bfhi(u.x); v2 += bflo(u.y); v3 += bfhi(u.y);
            }
        } else {  // statistically unreachable
            for (int k = ks; k < ke; ++k) {
                uint2 u = zp[(size_t)col[k] * 4 + sl];
                v0 += bflo(u.x); v1 += bfhi(u.x); v2 += bflo(u.y); v3 += bfhi(u.y);
            }
        }
        int c0 = sl * 4;
        sh[ln * 17 + c0 + 0] = fmaxf(v0 + sba[c0 + 0], 0.f);
        sh[ln * 17 + c0 + 1] = fmaxf(v1 + sba[c0 + 1], 0.f);
        sh[ln * 17 + c0 + 2] = fmaxf(v2 + sba[c0 + 2], 0.f);
        sh[ln * 17 + c0 + 3] = fmaxf(v3 + sba[c0 + 3], 0.f);
    }
    __syncthreads();

    if (act) {   // out channels 8*sl .. 8*sl+7 of o = h@Wb + bb
        int c0 = sl * 8;
        float o[8];
        #pragma unroll
        for (int j = 0; j < 8; ++j) o[j] = sbb[c0 + j];
        #pragma unroll
        for (int j = 0; j < 16; ++j) {
            float hj = sh[ln * 17 + j];
            #pragma unroll
            for (int cc = 0; cc < 8; ++cc)
                o[cc] += hj * sWb[j * 32 + c0 + cc];
        }
        if (CHAIN) {
            #pragma unroll
            for (int cc = 0; cc < 8; ++cc)
                sr[ln * 33 + c0 + cc] = fmaxf(o[cc], 0.f);
        } else {
            float* op = (float*)outv + (size_t)n * 32 + c0;
            #pragma unroll
            for (int cc = 0; cc < 8; ++cc)
                __builtin_nontemporal_store(o[cc], op + cc);
        }
    }
    if (CHAIN) {
        __syncthreads();
        if (act) {   // z_next channels 4*sl .. 4*sl+3 = ReLU(o) @ Wc
            int c0 = sl * 4;
            float a0 = 0.f, a1 = 0.f, a2 = 0.f, a3 = 0.f;
            #pragma unroll
            for (int j = 0; j < 32; ++j) {
                float rj = sr[ln * 33 + j];
                a0 += rj * sWc[j * 16 + c0 + 0];
                a1 += rj * sWc[j * 16 + c0 + 1];
                a2 += rj * sWc[j * 16 + c0 + 2];
                a3 += rj * sWc[j * 16 + c0 + 3];
            }
            uint_t p0 = (uint_t)f2bf(a0) | ((uint_t)f2bf(a1) << 16);
            uint_t p1 = (uint_t)f2bf(a2) | ((uint_t)f2bf(a3) << 16);
            uint_t* op = (uint_t*)outv + (size_t)n * 8 + sl * 2;
            op[0] = p0;    // cacheable: consumed by next conv's gather
            op[1] = p1;
        }
    }
}

// ---- Launch -------------------------------------------------------------

extern "C" void kernel_launch(void* const* d_in, const int* in_sizes, int n_in,
                              void* d_out, int out_size, void* d_ws, size_t ws_size,
                              hipStream_t stream) {
    const float* x  = (const float*)d_in[0];
    const int*   ei = (const int*)d_in[1];
    const float* W1 = (const float*)d_in[2];
    const float* b1 = (const float*)d_in[3];
    const float* W2 = (const float*)d_in[4];
    const float* b2 = (const float*)d_in[5];
    const float* W3 = (const float*)d_in[6];
    const float* b3 = (const float*)d_in[7];
    const float* W4 = (const float*)d_in[8];
    const float* b4 = (const float*)d_in[9];

    const int N = in_sizes[0] / 32;
    const int E = in_sizes[1] / 2;
    const int* src = ei;
    const int* dst = ei + E;

    const int NBKT = (N + BKT_NODES - 1) >> BKT_SHIFT;   // 391
    const int NBLK = (E + EPB - 1) / EPB;                // 306

    char* ws = (char*)d_ws;
    size_t o = 0;
    auto alloc = [&](size_t bytes) -> char* {
        o = (o + 255) & ~(size_t)255;
        char* r = ws + o;
        o += bytes;
        return r;
    };
    int*      hist   = (int*)     alloc(4 * (size_t)NBLK * NBKT);
    int*      T      = (int*)     alloc(4 * (size_t)NBKT);
    int*      Tscan  = (int*)     alloc(4 * (size_t)(NBKT + 1));
    int*      staged = (int*)     alloc(4 * (size_t)E);
    int*      rp     = (int*)     alloc(4 * (size_t)(N + 1));
    int*      col    = (int*)     alloc(4 * (size_t)E);
    ushort_t* zb     = (ushort_t*)alloc(2 * (size_t)N * 16);   // z1 = x@W1
    ushort_t* z2b    = (ushort_t*)alloc(2 * (size_t)N * 16);   // z2 = relu(out1)@W3

    lin_in<<<(N + 255) / 256, 256, 0, stream>>>((const float4*)x, W1, zb, N);

    histA<<<NBLK, 512, 0, stream>>>(dst, hist, E, NBKT);
    colscan<<<NBKT, 256, 0, stream>>>(hist, T, NBLK, NBKT);
    scan_small<<<1, 1024, 0, stream>>>(T, Tscan, NBKT, E);
    scatter_kernel<<<NBLK, 512, 0, stream>>>(src, dst, hist, Tscan, staged, E, NBKT);
    int q1 = N / 4, q2 = N / 2, q3 = (3 * N) / 4;
    fine_fill<<<NBKT, 256, 0, stream>>>(staged, Tscan, rp, col, N, E, NBKT, q1, q2, q3);

    agg_mlp16<true ><<<(N + NPB16 - 1) / NPB16, 256, 0, stream>>>(
        zb, rp, col, b1, W2, b2, W3, z2b, N);
    agg_mlp16<false><<<(N + NPB16 - 1) / NPB16, 256, 0, stream>>>(
        z2b, rp, col, b3, W4, b4, nullptr, d_out, N);
}